// Round 1
// baseline (2323.974 us; speedup 1.0000x reference)
//
#include <hip/hip_runtime.h>

typedef unsigned short u16;
typedef unsigned int u32;
typedef unsigned long long u64;

#define NB 8
#define NPTS 4096
#define MSEL 2048
#define NCENT (NB*MSEL)
#define KNBR 64
#define FEAT 64
#define FIN 67
#define HH 64
#define FOUT 128
#define CAND_CAP 192

#define KP1 96     // layer-1 K padded to 3x32
#define SA 104     // feat A-buffer row stride (bf16 elems)
#define S2 72      // h1/h2 row stride

#define FPT 512    // fps threads (8 waves, 2 per SIMD)

typedef __attribute__((ext_vector_type(8))) short short8;
typedef __attribute__((ext_vector_type(4))) float f32x4;

__device__ __forceinline__ float bf2f(u16 u) {
    union { u32 i; float f; } v; v.i = ((u32)u) << 16; return v.f;
}
__device__ __forceinline__ u16 f2bf(float f) {
    union { float f; u32 i; } v; v.f = f;
    u32 x = v.i;
    x += 0x7fffu + ((x >> 16) & 1u);
    return (u16)(x >> 16);
}
__device__ __forceinline__ void splitbf(float a, u16& hi, u16& lo) {
    u16 h = f2bf(a);
    hi = h;
    lo = f2bf(__fsub_rn(a, bf2f(h)));
}

// ---------------------------------------------------------------------------
// Packed (dist_bits, ~index) u64 argmax reduction steps via DPP.
// max over key == (max dist, then min index) — identical tie-break semantics
// to the verified two-pass (wave_max then wave_min) reduction.
// ---------------------------------------------------------------------------
template<int CTRL>
__device__ __forceinline__ void kstep(u32& hi, u32& lo) {
    int h2 = __builtin_amdgcn_update_dpp((int)hi, (int)hi, CTRL, 0xf, 0xf, false);
    int l2 = __builtin_amdgcn_update_dpp((int)lo, (int)lo, CTRL, 0xf, 0xf, false);
    u64 a = (((u64)hi) << 32) | (u64)lo;
    u64 c = (((u64)(u32)h2) << 32) | (u64)(u32)l2;
    if (c > a) { hi = (u32)h2; lo = (u32)l2; }
}

// merge step that also carries the winner's coordinates
template<int CTRL>
__device__ __forceinline__ void mstep(u32& hi, u32& lo, int& x, int& y, int& z) {
    int h2 = __builtin_amdgcn_update_dpp((int)hi, (int)hi, CTRL, 0xf, 0xf, false);
    int l2 = __builtin_amdgcn_update_dpp((int)lo, (int)lo, CTRL, 0xf, 0xf, false);
    int x2 = __builtin_amdgcn_update_dpp(x, x, CTRL, 0xf, 0xf, false);
    int y2 = __builtin_amdgcn_update_dpp(y, y, CTRL, 0xf, 0xf, false);
    int z2 = __builtin_amdgcn_update_dpp(z, z, CTRL, 0xf, 0xf, false);
    u64 a = (((u64)hi) << 32) | (u64)lo;
    u64 c = (((u64)(u32)h2) << 32) | (u64)(u32)l2;
    if (c > a) { hi = (u32)h2; lo = (u32)l2; x = x2; y = y2; z = z2; }
}

// ---------------------------------------------------------------------------
// Kernel 1: exact FPS, latency-restructured.
// 512 threads / 8 waves (2 per SIMD), 8 pts/thread. Same exact arithmetic
// (__fsub_rn/__fmul_rn/__fadd_rn sum-of-squares, fminf) and the same global
// (max dist, min index) selection order as the verified r13 kernel, so the
// selected sequence is bit-identical. Changes are purely structural:
//   - in-thread argmax is a depth-3 tree (was 16-deep serial chain)
//   - wave reduce is one packed-u64 6-step DPP pass (was max-pass + min-pass)
//   - cross-wave merge is wave-parallel: 3 DPP steps over 8 LDS candidates
// ---------------------------------------------------------------------------
__global__ __launch_bounds__(FPT) void fps_kernel(const float* __restrict__ pos,
        int* __restrict__ sel, float* __restrict__ pos_out,
        float* __restrict__ batch_out) {
    __shared__ float px[NPTS], py[NPTS], pz[NPTS];
    __shared__ int hist[MSEL];
    __shared__ int4  cA[2][8];    // {keyhi, keylo, xbits, ybits} per wave
    __shared__ float cZ[2][8];
    const int b = blockIdx.x, t = threadIdx.x;
    const int wid = t >> 6, lane = t & 63;
    const float* pb = pos + (long)b * NPTS * 3;

    for (int i = t; i < NPTS; i += FPT) {
        px[i] = pb[i*3+0]; py[i] = pb[i*3+1]; pz[i] = pb[i*3+2];
    }
    __syncthreads();

    float rx[8], ry[8], rz[8], md[8];
    #pragma unroll
    for (int j = 0; j < 8; ++j) {
        int i = t + FPT*j;
        rx[j] = px[i]; ry[j] = py[i]; rz[j] = pz[i];
        md[j] = __builtin_inff();
    }

    int cur = 0;
    float cx = px[0], cy = py[0], cz = pz[0];
    for (int s = 0; s < MSEL; ++s) {
        const int p = s & 1;
        if (t == 0) hist[s] = cur;
        #pragma unroll
        for (int j = 0; j < 8; ++j) {
            float dx = __fsub_rn(rx[j], cx);
            float dy = __fsub_rn(ry[j], cy);
            float dz = __fsub_rn(rz[j], cz);
            float d  = __fadd_rn(__fadd_rn(__fmul_rn(dx,dx), __fmul_rn(dy,dy)),
                                 __fmul_rn(dz,dz));
            md[j] = fminf(md[j], d);
        }
        // in-thread argmax tree; strict > everywhere -> lowest j wins ties,
        // and local indices are monotone in j, preserving first-occurrence.
        float vA = md[0]; int iA = 0;
        if (md[1] > vA) { vA = md[1]; iA = 1; }
        float vB = md[2]; int iB = 2;
        if (md[3] > vB) { vB = md[3]; iB = 3; }
        if (vB > vA) { vA = vB; iA = iB; }
        float vC = md[4]; int iC = 4;
        if (md[5] > vC) { vC = md[5]; iC = 5; }
        float vD = md[6]; int iD = 6;
        if (md[7] > vD) { vD = md[7]; iD = 7; }
        if (vD > vC) { vC = vD; iC = iD; }
        if (vC > vA) { vA = vC; iA = iC; }

        // packed key: dist (>=0, so float order == int order) desc, index asc
        u32 hi = __float_as_uint(vA);
        u32 lo = ~(u32)(t + (iA << 9));
        kstep<0x111>(hi, lo); kstep<0x112>(hi, lo); kstep<0x114>(hi, lo);
        kstep<0x118>(hi, lo); kstep<0x142>(hi, lo); kstep<0x143>(hi, lo);
        const u32 klo = (u32)__builtin_amdgcn_readlane((int)lo, 63);
        const u32 khi = (u32)__builtin_amdgcn_readlane((int)hi, 63);
        const int Iw = (int)~klo;
        if (t == (Iw & (FPT-1))) {             // owner thread carries coords
            const int j = Iw >> 9;
            cA[p][wid] = make_int4((int)khi, (int)klo,
                                   __float_as_int(rx[j]), __float_as_int(ry[j]));
            cZ[p][wid] = rz[j];
        }
        __syncthreads();
        // wave-parallel merge of the 8 wave candidates (entries duplicated
        // every 8 lanes; row_shr 1/2/4 leaves the full max in lane 7)
        int4 e = cA[p][lane & 7];
        u32 mh = (u32)e.x, ml = (u32)e.y;
        int mx = e.z, my = e.w, mz = __float_as_int(cZ[p][lane & 7]);
        mstep<0x111>(mh, ml, mx, my, mz);
        mstep<0x112>(mh, ml, mx, my, mz);
        mstep<0x114>(mh, ml, mx, my, mz);
        cur = (int)~(u32)__builtin_amdgcn_readlane((int)ml, 7);
        cx = __int_as_float(__builtin_amdgcn_readlane(mx, 7));
        cy = __int_as_float(__builtin_amdgcn_readlane(my, 7));
        cz = __int_as_float(__builtin_amdgcn_readlane(mz, 7));
    }
    __syncthreads();
    for (int g = t; g < MSEL; g += FPT) {
        int i = hist[g];
        int o = b * MSEL + g;
        sel[o] = i;
        pos_out[o*3+0] = px[i]; pos_out[o*3+1] = py[i]; pos_out[o*3+2] = pz[i];
        batch_out[o] = (float)b;
    }
}

// ---------------------------------------------------------------------------
// Kernel 1.5: weight pre-transform (unchanged, verified).
// ---------------------------------------------------------------------------
__global__ __launch_bounds__(256) void wcvt_kernel(const float* __restrict__ W1,
        const float* __restrict__ W2, const float* __restrict__ W3,
        u16* __restrict__ w1h, u16* __restrict__ w1l,
        u16* __restrict__ w2h, u16* __restrict__ w2l,
        u16* __restrict__ w3h, u16* __restrict__ w3l) {
    int t = blockIdx.x * 256 + threadIdx.x;
    if (t < 64*KP1) {
        int n = t / KP1, k = t % KP1;
        u16 h, l; splitbf((k < FIN) ? W1[(long)k*HH + n] : 0.0f, h, l);
        w1h[t] = h; w1l[t] = l;
    }
    if (t < 64*64) {
        int n = t / 64, k = t % 64;
        u16 h, l; splitbf(W2[(long)k*HH + n], h, l);
        w2h[t] = h; w2l[t] = l;
    }
    if (t < 128*64) {
        int n = t / 64, k = t % 64;
        u16 h, l; splitbf(W3[(long)k*FOUT + n], h, l);
        w3h[t] = h; w3l[t] = l;
    }
}

// ---------------------------------------------------------------------------
// Kernel 2: fused radius + PointNetConv + max-pool, COLUMN-PARTITIONED waves.
// (unchanged, verified; absmax tripwire: exactly 0.015625)
// ---------------------------------------------------------------------------
__global__ __launch_bounds__(256) void conv_kernel(const float* __restrict__ x,
        const float* __restrict__ pos, const int* __restrict__ sel,
        const u16* __restrict__ w1h, const u16* __restrict__ w1l,
        const u16* __restrict__ w2h, const u16* __restrict__ w2l,
        const u16* __restrict__ w3h, const u16* __restrict__ w3l,
        const float* __restrict__ b1, const float* __restrict__ b2,
        const float* __restrict__ b3, float* __restrict__ xout) {
    __shared__ __align__(16) u16 fAh[64*SA], fAl[64*SA];   // feat, then h2 (stride S2)
    __shared__ __align__(16) u16 h1h[64*S2], h1l[64*S2];
    __shared__ float cdv[CAND_CAP];
    __shared__ int   cixv[CAND_CAP];
    __shared__ int   snbr[KNBR];
    __shared__ int   sc[2];
    const int c = blockIdx.x, t = threadIdx.x;
    const int b = c >> 11;
    const int lane = t & 63, w = t >> 6;
    const int colc = lane & 15;
    const float* pb = pos + (long)b * NPTS * 3;
    const int j0 = sel[c];
    const float qx = pb[j0*3+0], qy = pb[j0*3+1], qz = pb[j0*3+2];

    const int nw = w*16 + colc;            // this wave's column (layers 1-2)
    const float bias1 = b1[nw];
    const float bias2 = b2[nw];
    const float bias3[2] = { b3[(2*w+0)*16 + colc], b3[(2*w+1)*16 + colc] };

    if (t == 0) { sc[0] = 0; sc[1] = 0; }
    __syncthreads();

    // ---- radius gather (bit-exact; verified r4-r13)
    const float R2 = (float)(0.15 * 0.15);
    for (int it = 0; it < NPTS/256; ++it) {
        int i = t + 256*it;
        float dx = __fsub_rn(qx, pb[i*3+0]);
        float dy = __fsub_rn(qy, pb[i*3+1]);
        float dz = __fsub_rn(qz, pb[i*3+2]);
        float d2 = __fadd_rn(__fadd_rn(__fmul_rn(dx,dx), __fmul_rn(dy,dy)),
                             __fmul_rn(dz,dz));
        if (d2 <= R2) {
            int slot = atomicAdd(&sc[0], 1);
            if (slot < CAND_CAP) { cdv[slot] = d2; cixv[slot] = i; }
        }
    }
    __syncthreads();
    int C = sc[0]; if (C > CAND_CAP) C = CAND_CAP;
    int cnt;
    if (C <= KNBR) {
        for (int e = t; e < C; e += 256) snbr[e] = cixv[e];
        cnt = C;
    } else {
        for (int e = t; e < C; e += 256) {
            float de = cdv[e]; int ie = cixv[e];
            int rank = 0;
            for (int f = 0; f < C; ++f) {
                float df = cdv[f]; int jf = cixv[f];
                rank += (df < de || (df == de && jf < ie)) ? 1 : 0;
            }
            if (rank < KNBR) {
                int slot = atomicAdd(&sc[1], 1);
                snbr[slot] = ie;
            }
        }
        cnt = KNBR;
    }
    __syncthreads();

    // ---- stage features (4 threads/row); zero K-pad cols 67..99
    const int kk = t >> 2, sub = t & 3;
    if (kk < cnt) {
        int j = snbr[kk];
        const float4* xr4 = (const float4*)(x + ((long)b*NPTS + j) * FEAT);
        #pragma unroll
        for (int i = 0; i < 4; ++i) {
            int ci = sub*4 + i;
            float4 v = xr4[ci];
            u16 h0,l0,h1_,l1_,h2_,l2_,h3_,l3_;
            splitbf(v.x, h0, l0); splitbf(v.y, h1_, l1_);
            splitbf(v.z, h2_, l2_); splitbf(v.w, h3_, l3_);
            int o = kk*SA + ci*4;
            fAh[o+0]=h0; fAh[o+1]=h1_; fAh[o+2]=h2_; fAh[o+3]=h3_;
            fAl[o+0]=l0; fAl[o+1]=l1_; fAl[o+2]=l2_; fAl[o+3]=l3_;
        }
        if (sub < 3) {
            float qv = (sub == 0) ? qx : ((sub == 1) ? qy : qz);
            u16 h, l; splitbf(__fsub_rn(pb[j*3+sub], qv), h, l);
            fAh[kk*SA + 64 + sub] = h; fAl[kk*SA + 64 + sub] = l;
        } else {
            fAh[kk*SA + 67] = 0; fAl[kk*SA + 67] = 0;
        }
        u32* zh = (u32*)&fAh[kk*SA + 68];
        u32* zl = (u32*)&fAl[kk*SA + 68];
        #pragma unroll
        for (int i2 = 0; i2 < 4; ++i2) { zh[sub + 4*i2] = 0; zl[sub + 4*i2] = 0; }
    }
    __syncthreads();   // layer 1 reads ALL rows -> full barrier

    const int mL = lane & 15;              // A-row within a 16-row tile
    const int kq = (lane >> 4) * 8;
    const int rgrp = (lane >> 4) * 4;

    // ---- B-fragment loads: this wave's column stripe only (18 KB/wave)
    short8 B1h[3], B1l[3], B2h[2], B2l[2], B3h[2][2], B3l[2][2];
    #pragma unroll
    for (int i = 0; i < 3; ++i) {
        B1h[i] = *(const short8*)&w1h[nw*KP1 + i*32 + kq];
        B1l[i] = *(const short8*)&w1l[nw*KP1 + i*32 + kq];
    }
    #pragma unroll
    for (int i = 0; i < 2; ++i) {
        B2h[i] = *(const short8*)&w2h[nw*64 + i*32 + kq];
        B2l[i] = *(const short8*)&w2l[nw*64 + i*32 + kq];
    }

    // ---- layer 1: 96(67) -> 64, all 4 row-tiles, cols nw
    #pragma unroll
    for (int rt = 0; rt < 4; ++rt) {
        short8 ah[3], al[3];
        #pragma unroll
        for (int i = 0; i < 3; ++i) {
            ah[i] = *(const short8*)&fAh[(rt*16 + mL)*SA + i*32 + kq];
            al[i] = *(const short8*)&fAl[(rt*16 + mL)*SA + i*32 + kq];
        }
        f32x4 acc = {bias1, bias1, bias1, bias1};
        #pragma unroll
        for (int i = 0; i < 3; ++i)
            acc = __builtin_amdgcn_mfma_f32_16x16x32_bf16(ah[i], B1h[i], acc, 0,0,0);
        #pragma unroll
        for (int i = 0; i < 3; ++i)
            acc = __builtin_amdgcn_mfma_f32_16x16x32_bf16(ah[i], B1l[i], acc, 0,0,0);
        #pragma unroll
        for (int i = 0; i < 3; ++i)
            acc = __builtin_amdgcn_mfma_f32_16x16x32_bf16(al[i], B1h[i], acc, 0,0,0);
        #pragma unroll
        for (int r = 0; r < 4; ++r) {
            u16 h, l; splitbf(fmaxf(acc[r], 0.0f), h, l);
            int mr = rt*16 + rgrp + r;
            h1h[mr*S2 + nw] = h; h1l[mr*S2 + nw] = l;
        }
    }
    // prefetch layer-3 B while layer-1 results drain
    #pragma unroll
    for (int j = 0; j < 2; ++j) {
        int n3 = (2*w + j)*16 + colc;
        #pragma unroll
        for (int i = 0; i < 2; ++i) {
            B3h[j][i] = *(const short8*)&w3h[n3*64 + i*32 + kq];
            B3l[j][i] = *(const short8*)&w3l[n3*64 + i*32 + kq];
        }
    }
    __syncthreads();

    // ---- layer 2: 64 -> 64 (h2 overwrites fA, stride S2)
    #pragma unroll
    for (int rt = 0; rt < 4; ++rt) {
        short8 ah[2], al[2];
        #pragma unroll
        for (int i = 0; i < 2; ++i) {
            ah[i] = *(const short8*)&h1h[(rt*16 + mL)*S2 + i*32 + kq];
            al[i] = *(const short8*)&h1l[(rt*16 + mL)*S2 + i*32 + kq];
        }
        f32x4 acc = {bias2, bias2, bias2, bias2};
        #pragma unroll
        for (int i = 0; i < 2; ++i)
            acc = __builtin_amdgcn_mfma_f32_16x16x32_bf16(ah[i], B2h[i], acc, 0,0,0);
        #pragma unroll
        for (int i = 0; i < 2; ++i)
            acc = __builtin_amdgcn_mfma_f32_16x16x32_bf16(ah[i], B2l[i], acc, 0,0,0);
        #pragma unroll
        for (int i = 0; i < 2; ++i)
            acc = __builtin_amdgcn_mfma_f32_16x16x32_bf16(al[i], B2h[i], acc, 0,0,0);
        #pragma unroll
        for (int r = 0; r < 4; ++r) {
            u16 h, l; splitbf(fmaxf(acc[r], 0.0f), h, l);
            int mr = rt*16 + rgrp + r;
            fAh[mr*S2 + nw] = h; fAl[mr*S2 + nw] = l;
        }
    }
    __syncthreads();

    // ---- layer 3: 64 -> 128, 2 col stripes/wave, fused relu + masked pool
    #pragma unroll
    for (int j = 0; j < 2; ++j) {
        const float bb = bias3[j];
        float v = 0.0f;   // relu >= 0 and cnt >= 1 -> 0 is identity
        #pragma unroll
        for (int rt = 0; rt < 4; ++rt) {
            short8 ah[2], al[2];
            #pragma unroll
            for (int i = 0; i < 2; ++i) {
                ah[i] = *(const short8*)&fAh[(rt*16 + mL)*S2 + i*32 + kq];
                al[i] = *(const short8*)&fAl[(rt*16 + mL)*S2 + i*32 + kq];
            }
            f32x4 acc = {bb, bb, bb, bb};
            #pragma unroll
            for (int i = 0; i < 2; ++i)
                acc = __builtin_amdgcn_mfma_f32_16x16x32_bf16(ah[i], B3h[j][i], acc, 0,0,0);
            #pragma unroll
            for (int i = 0; i < 2; ++i)
                acc = __builtin_amdgcn_mfma_f32_16x16x32_bf16(ah[i], B3l[j][i], acc, 0,0,0);
            #pragma unroll
            for (int i = 0; i < 2; ++i)
                acc = __builtin_amdgcn_mfma_f32_16x16x32_bf16(al[i], B3h[j][i], acc, 0,0,0);
            #pragma unroll
            for (int r = 0; r < 4; ++r) {
                int m = rt*16 + rgrp + r;
                float hv = fmaxf(acc[r], 0.0f);
                v = (m < cnt) ? fmaxf(v, hv) : v;
            }
        }
        v = fmaxf(v, __shfl_xor(v, 16, 64));
        v = fmaxf(v, __shfl_xor(v, 32, 64));
        if (lane < 16)
            xout[(long)c*FOUT + (2*w + j)*16 + lane] = v;
    }
}

// ---------------------------------------------------------------------------
extern "C" void kernel_launch(void* const* d_in, const int* in_sizes, int n_in,
                              void* d_out, int out_size, void* d_ws, size_t ws_size,
                              hipStream_t stream) {
    const float* x   = (const float*)d_in[0];
    const float* pos = (const float*)d_in[1];
    const float* W1 = (const float*)d_in[3];
    const float* b1 = (const float*)d_in[4];
    const float* W2 = (const float*)d_in[5];
    const float* b2 = (const float*)d_in[6];
    const float* W3 = (const float*)d_in[7];
    const float* b3 = (const float*)d_in[8];

    float* out       = (float*)d_out;
    float* xout      = out;
    float* pos_out   = out + (long)NCENT * FOUT;
    float* batch_out = pos_out + (long)NCENT * 3;

    int* sel = (int*)d_ws;
    u16* w1h = (u16*)((char*)d_ws + 65536);
    u16* w1l = w1h + 64*KP1;
    u16* w2h = w1l + 64*KP1;
    u16* w2l = w2h + 64*64;
    u16* w3h = w2l + 64*64;
    u16* w3l = w3h + 128*64;

    wcvt_kernel<<<32, 256, 0, stream>>>(W1, W2, W3, w1h, w1l, w2h, w2l, w3h, w3l);
    fps_kernel<<<NB, FPT, 0, stream>>>(pos, sel, pos_out, batch_out);
    conv_kernel<<<NCENT, 256, 0, stream>>>(x, pos, sel, w1h, w1l, w2h, w2l,
                                           w3h, w3l, b1, b2, b3, xout);
}